// Round 1
// 361.689 us; speedup vs baseline: 1.2964x; 1.2964x over previous
//
#include <hip/hip_runtime.h>
#include <math.h>

// Problem constants
#define BB   16
#define TT   4
#define CC   2048
#define NH   16
#define NKV  4
#define DH   128
#define GRP  4
#define SCACHE 4096
#define SATT 2052          // sink(4) + window(2048)
#define CS   128           // keys per attention chunk
#define NCH  17            // ceil(2052/128)
#define KSPL 8             // K-split for the two GEMMs (slice = 256)

typedef unsigned int  uint32;
typedef unsigned short ushort_t;
typedef __attribute__((ext_vector_type(8))) __bf16 bf16x8;
typedef __attribute__((ext_vector_type(4))) float  f32x4;

__device__ __forceinline__ uint32 f2bf_bits(float f) {
    uint32 u = __float_as_uint(f);
    return (u + 0x7FFFu + ((u >> 16) & 1u)) >> 16;   // RN-even
}
__device__ __forceinline__ uint32 pk2(float lo, float hi) {
    return f2bf_bits(lo) | (f2bf_bits(hi) << 16);
}

// ---- Workspace layout (bytes) ---- (same 10.5 MB footprint, known-safe)
#define Q_OFF    0
#define KNEW_OFF 524288
#define VNEW_OFF 655360
#define Y_OFF    786432
#define SCR_OFF  1310720

// -------- Kernel 1: QKV GEMM --------------------------------------------------
// All 64 rows per block (weights read exactly once), 64-col tile, K-split 8.
// grid (48, 8): x = col-tile, y = k-slice of 256.
__global__ __launch_bounds__(256) void k_qkv(
    const float* __restrict__ x, const float* __restrict__ wq,
    const float* __restrict__ wk, const float* __restrict__ wv,
    float* __restrict__ part_qkv)
{
    __shared__ float xs[64][256];          // 64 KB
    int ns = blockIdx.x, ks = blockIdx.y;
    int tid = threadIdx.x;
    int k0 = ks * 256;

    #pragma unroll
    for (int it = 0; it < 16; ++it) {
        int slot = it * 256 + tid;          // 4096 float4 slots
        int row = slot >> 6, c4 = slot & 63;
        *(float4*)&xs[row][c4 * 4] = *(const float4*)(x + (size_t)row * CC + k0 + c4 * 4);
    }
    __syncthreads();

    int cp = tid & 31, rg = tid >> 5;       // col pair, row group of 8
    const float* wp; int ldw, col;
    if (ns < 32)      { ldw = 2048; col = ns * 64 + cp * 2;
                        wp = wq + (size_t)k0 * 2048 + ns * 64 + cp * 2; }
    else if (ns < 40) { ldw = 512;  col = 2048 + (ns - 32) * 64 + cp * 2;
                        wp = wk + (size_t)k0 * 512 + (ns - 32) * 64 + cp * 2; }
    else              { ldw = 512;  col = 2560 + (ns - 40) * 64 + cp * 2;
                        wp = wv + (size_t)k0 * 512 + (ns - 40) * 64 + cp * 2; }

    float a[16];
    #pragma unroll
    for (int i = 0; i < 16; ++i) a[i] = 0.f;

    for (int k = 0; k < 256; k += 4) {
        float2 w0 = *(const float2*)(wp);
        float2 w1 = *(const float2*)(wp + ldw);
        float2 w2 = *(const float2*)(wp + 2 * ldw);
        float2 w3 = *(const float2*)(wp + 3 * ldw);
        wp += 4 * ldw;
        #pragma unroll
        for (int m = 0; m < 8; ++m) {
            float4 xv = *(const float4*)&xs[rg * 8 + m][k];
            float s0 = a[2*m], s1 = a[2*m+1];
            s0 = fmaf(xv.x, w0.x, s0); s1 = fmaf(xv.x, w0.y, s1);
            s0 = fmaf(xv.y, w1.x, s0); s1 = fmaf(xv.y, w1.y, s1);
            s0 = fmaf(xv.z, w2.x, s0); s1 = fmaf(xv.z, w2.y, s1);
            s0 = fmaf(xv.w, w3.x, s0); s1 = fmaf(xv.w, w3.y, s1);
            a[2*m] = s0; a[2*m+1] = s1;
        }
    }
    #pragma unroll
    for (int m = 0; m < 8; ++m)
        *(float2*)(part_qkv + ((size_t)(ks * 64 + rg * 8 + m) * 3072) + col) =
            make_float2(a[2*m], a[2*m+1]);
}

// -------- Kernel 2: combine K-split partials + RoPE (8 splits now) -------------
__global__ __launch_bounds__(256) void k_fix(
    const float* __restrict__ part_qkv, const int* __restrict__ spp,
    float* __restrict__ qws, float* __restrict__ knew, float* __restrict__ vnew)
{
    int u = blockIdx.x * 256 + threadIdx.x;
    int m = blockIdx.y;
    int b = m >> 2, t = m & 3;
    int sp = spp[0];
    const float NEG_L2_10K_64 = -0.20762050593048633f;

    if (u < 1024) {
        int h = u >> 6, d = u & 63;
        int col = h * 128 + d;
        float s1 = 0.f, s2 = 0.f;
        #pragma unroll
        for (int ks = 0; ks < KSPL; ++ks) {
            const float* p = part_qkv + (size_t)(ks * 64 + m) * 3072;
            s1 += p[col]; s2 += p[col + 64];
        }
        float inv = exp2f((float)d * NEG_L2_10K_64);
        float ang = (float)(sp + t) * inv;
        float cc = cosf(ang), ss = sinf(ang);
        float* dst = qws + (size_t)((b * NH + h) * TT + t) * DH + d;
        dst[0]  = s1 * cc - s2 * ss;
        dst[64] = s1 * ss + s2 * cc;
    } else if (u < 1280) {
        int v = u - 1024;
        int kv = v >> 6, d = v & 63;
        int col = 2048 + kv * 128 + d;
        float s1 = 0.f, s2 = 0.f;
        #pragma unroll
        for (int ks = 0; ks < KSPL; ++ks) {
            const float* p = part_qkv + (size_t)(ks * 64 + m) * 3072;
            s1 += p[col]; s2 += p[col + 64];
        }
        float inv = exp2f((float)d * NEG_L2_10K_64);
        float ang = (float)(sp + t) * inv;
        float cc = cosf(ang), ss = sinf(ang);
        float* dst = knew + (size_t)((b * NKV + kv) * TT + t) * DH + d;
        dst[0]  = s1 * cc - s2 * ss;
        dst[64] = s1 * ss + s2 * cc;
    } else {
        int v = u - 1280;
        int c0 = v * 2;
        int kv = c0 >> 7, dd = c0 & 127;
        float s1 = 0.f, s2 = 0.f;
        #pragma unroll
        for (int ks = 0; ks < KSPL; ++ks) {
            const float* p = part_qkv + (size_t)(ks * 64 + m) * 3072 + 2560 + c0;
            s1 += p[0]; s2 += p[1];
        }
        float* dst = vnew + (size_t)((b * NKV + kv) * TT + t) * DH + dd;
        dst[0] = s1; dst[1] = s2;
    }
}

// key/value row j in [0, 2052)
__device__ __forceinline__ const float* kv_row(
    const float* cache, const float* newt, int bk, int j)
{
    if (j < 4)         return cache + ((size_t)bk * SCACHE + j) * DH;
    else if (j < 2048) return cache + ((size_t)bk * SCACHE + j + 2048) * DH;
    else               return newt  + ((size_t)(bk * TT + (j - 2048))) * DH;
}

// -------- Kernel 3: MFMA flash-decode attention partials -----------------------
// Changes vs prior: softmax in-register (s_f dropped -> LDS 39680, 4 blk/CU
// possible), V loads issued before first barrier (T14), barriers 4 -> 3.
// Verified layouts: A[m=lane&15][k=quad*8+j], B[k=quad*8+j][n=lane&15],
// C/D[row=quad*4+reg][col=lane&15].
__global__ __launch_bounds__(256) void k_attn(
    const float* __restrict__ qws,
    const float* __restrict__ kc, const float* __restrict__ vc,
    const float* __restrict__ knew, const float* __restrict__ vnew,
    float* __restrict__ part)
{
    __shared__ ushort_t kv_lds[128 * 136];   // 34816 B: K rows, then V^T rows
    __shared__ ushort_t p_lds[16 * 136];     // 4352 B: P in bf16, A-layout
    __shared__ float    red_a[64];           // [wave][row] partial max
    __shared__ float    red_b[64];           // [wave][row] partial sum

    int bx = blockIdx.x;
    int c  = bx % NCH;
    int bk = bx / NCH;
    int b  = bk >> 2, kvh = bk & 3;
    int j0 = c * CS;
    int jn = (SATT - j0 < CS) ? (SATT - j0) : CS;
    int tid  = threadIdx.x;
    int wave = tid >> 6, lane = tid & 63;
    int quad = lane >> 4, l15 = lane & 15;
    const float scale = 0.08838834764831845f;   // 1/sqrt(128)

    // ---- Q fragments straight to registers (same for all waves) ----
    bf16x8 aq[4];
    {
        int h = kvh * GRP + (l15 >> 2), t = l15 & 3;
        const float* qr = qws + (size_t)((b * NH + h) * TT + t) * DH;
        #pragma unroll
        for (int ks = 0; ks < 4; ++ks) {
            const float* s = qr + ks * 32 + quad * 8;
            float4 f0 = *(const float4*)s;
            float4 f1 = *(const float4*)(s + 4);
            union { uint32 u[4]; bf16x8 v; } pk;
            pk.u[0] = pk2(f0.x, f0.y); pk.u[1] = pk2(f0.z, f0.w);
            pk.u[2] = pk2(f1.x, f1.y); pk.u[3] = pk2(f1.z, f1.w);
            aq[ks] = pk.v;
        }
    }

    // ---- stage K tile: burst all 16 loads, then pack -> bf16 LDS ----
    {
        float4 kf[16];
        #pragma unroll
        for (int it = 0; it < 8; ++it) {
            int slot = it * 256 + tid;
            int row = slot >> 4, d0 = (slot & 15) * 8;
            const float* kr = kv_row(kc, knew, bk, j0 + (row < jn ? row : 0)) + d0;
            kf[2*it]   = *(const float4*)kr;
            kf[2*it+1] = *(const float4*)(kr + 4);
        }
        #pragma unroll
        for (int it = 0; it < 8; ++it) {
            int slot = it * 256 + tid;
            int row = slot >> 4, d0 = (slot & 15) * 8;
            union { uint32 u[4]; bf16x8 v; } pk;
            pk.u[0] = pk.u[1] = pk.u[2] = pk.u[3] = 0;
            if (row < jn) {
                pk.u[0] = pk2(kf[2*it].x, kf[2*it].y);
                pk.u[1] = pk2(kf[2*it].z, kf[2*it].w);
                pk.u[2] = pk2(kf[2*it+1].x, kf[2*it+1].y);
                pk.u[3] = pk2(kf[2*it+1].z, kf[2*it+1].w);
            }
            *(bf16x8*)&kv_lds[row * 136 + d0] = pk.v;
        }
    }
    __syncthreads();

    // ---- QK^T: wave handles key-cols [wave*32, wave*32+32) ----
    int n0 = wave * 32;
    f32x4 s0 = {0.f, 0.f, 0.f, 0.f}, s1 = {0.f, 0.f, 0.f, 0.f};
    #pragma unroll
    for (int ks = 0; ks < 4; ++ks) {
        bf16x8 b0 = *(const bf16x8*)&kv_lds[(n0 + l15) * 136 + ks * 32 + quad * 8];
        bf16x8 b1 = *(const bf16x8*)&kv_lds[(n0 + 16 + l15) * 136 + ks * 32 + quad * 8];
        s0 = __builtin_amdgcn_mfma_f32_16x16x32_bf16(aq[ks], b0, s0, 0, 0, 0);
        s1 = __builtin_amdgcn_mfma_f32_16x16x32_bf16(aq[ks], b1, s1, 0, 0, 0);
    }

    // ---- issue V loads NOW (latency hides under softmax + barrier) ----
    float4 va[8], vb[8];
    int key0 = 2 * lane;
    bool okA = key0 < jn, okB = key0 + 1 < jn;
    {
        const float* ra = kv_row(vc, vnew, bk, j0 + (okA ? key0 : 0));
        const float* rb = kv_row(vc, vnew, bk, j0 + (okB ? key0 + 1 : 0));
        #pragma unroll
        for (int i = 0; i < 8; ++i) {
            int d = wave * 32 + i * 4;
            va[i] = *(const float4*)(ra + d);
            vb[i] = *(const float4*)(rb + d);
        }
    }

    // ---- scale + mask scores; quad-local row max via shfl_xor ----
    int c0 = n0 + l15, c1 = n0 + 16 + l15;
    bool v0ok = c0 < jn, v1ok = c1 < jn;
    float sc0[4], sc1[4];
    #pragma unroll
    for (int i = 0; i < 4; ++i) {
        sc0[i] = v0ok ? s0[i] * scale : -1e30f;
        sc1[i] = v1ok ? s1[i] * scale : -1e30f;
        float v = fmaxf(sc0[i], sc1[i]);
        v = fmaxf(v, __shfl_xor(v, 1));
        v = fmaxf(v, __shfl_xor(v, 2));
        v = fmaxf(v, __shfl_xor(v, 4));
        v = fmaxf(v, __shfl_xor(v, 8));
        if (l15 == 0) red_a[wave * 16 + quad * 4 + i] = v;
    }
    __syncthreads();   // K reads done (V^T writes now safe); red_a complete

    // ---- finish softmax in-register; P -> bf16 A-layout in p_lds ----
    #pragma unroll
    for (int i = 0; i < 4; ++i) {
        int r = quad * 4 + i;
        float M = fmaxf(fmaxf(red_a[r], red_a[16 + r]),
                        fmaxf(red_a[32 + r], red_a[48 + r]));
        float p0 = __expf(sc0[i] - M);     // masked cols: exp(-huge) = 0
        float p1 = __expf(sc1[i] - M);
        p_lds[r * 136 + c0] = (ushort_t)f2bf_bits(p0);
        p_lds[r * 136 + c1] = (ushort_t)f2bf_bits(p1);
        float v = p0 + p1;
        v += __shfl_xor(v, 1);
        v += __shfl_xor(v, 2);
        v += __shfl_xor(v, 4);
        v += __shfl_xor(v, 8);
        if (l15 == 0) red_b[wave * 16 + r] = v;
    }

    // ---- write V^T (pair-packed bf16) into kv_lds ----
    {
        uint32* vt32 = (uint32*)kv_lds;
        #pragma unroll
        for (int i = 0; i < 8; ++i) {
            int d = wave * 32 + i * 4;
            float4 fa = okA ? va[i] : make_float4(0.f, 0.f, 0.f, 0.f);
            float4 fb = okB ? vb[i] : make_float4(0.f, 0.f, 0.f, 0.f);
            vt32[(d + 0) * 68 + lane] = pk2(fa.x, fb.x);
            vt32[(d + 1) * 68 + lane] = pk2(fa.y, fb.y);
            vt32[(d + 2) * 68 + lane] = pk2(fa.z, fb.z);
            vt32[(d + 3) * 68 + lane] = pk2(fa.w, fb.w);
        }
    }
    __syncthreads();   // p_lds + V^T + red_b all visible

    // ---- per-row M, L to partials ----
    if (tid < 16) {
        int r = tid;
        float M = fmaxf(fmaxf(red_a[r], red_a[16 + r]),
                        fmaxf(red_a[32 + r], red_a[48 + r]));
        float L = red_b[r] + red_b[16 + r] + red_b[32 + r] + red_b[48 + r];
        float* rp = part + ((size_t)(bk * NCH + c) * 16 + r) * 132;
        rp[0] = M; rp[1] = L;
    }

    // ---- PV: wave handles d-cols [wave*32, wave*32+32) ----
    int d0 = wave * 32;
    f32x4 o0 = {0.f, 0.f, 0.f, 0.f}, o1 = {0.f, 0.f, 0.f, 0.f};
    #pragma unroll
    for (int ks = 0; ks < 4; ++ks) {
        bf16x8 ap = *(const bf16x8*)&p_lds[l15 * 136 + ks * 32 + quad * 8];
        bf16x8 b0 = *(const bf16x8*)&kv_lds[(d0 + l15) * 136 + ks * 32 + quad * 8];
        bf16x8 b1 = *(const bf16x8*)&kv_lds[(d0 + 16 + l15) * 136 + ks * 32 + quad * 8];
        o0 = __builtin_amdgcn_mfma_f32_16x16x32_bf16(ap, b0, o0, 0, 0, 0);
        o1 = __builtin_amdgcn_mfma_f32_16x16x32_bf16(ap, b1, o1, 0, 0, 0);
    }
    float* dstb = part + (size_t)(bk * NCH + c) * 16 * 132;
    #pragma unroll
    for (int i = 0; i < 4; ++i) {
        int row = quad * 4 + i;
        dstb[row * 132 + 4 + d0 + l15]      = o0[i];
        dstb[row * 132 + 4 + d0 + 16 + l15] = o1[i];
    }
}

// -------- Kernel 4: combine chunk partials -> yws (unchanged) ------------------
__global__ __launch_bounds__(128) void k_comb(
    const float* __restrict__ part, float* __restrict__ yws)
{
    int bx = blockIdx.x;
    int t = bx & 3, h = (bx >> 2) & 15, b = bx >> 6;
    int bk = b * NKV + (h >> 2);
    int r  = (h & 3) * 4 + t;
    int d  = threadIdx.x;
    float M = -1e30f;
    for (int c = 0; c < NCH; ++c)
        M = fmaxf(M, part[((size_t)(bk * NCH + c) * 16 + r) * 132]);
    float L = 0.f, y = 0.f;
    for (int c = 0; c < NCH; ++c) {
        const float* pp = part + ((size_t)(bk * NCH + c) * 16 + r) * 132;
        float w = __expf(pp[0] - M);
        L += w * pp[1];
        y  = fmaf(w, pp[4 + d], y);
    }
    yws[(size_t)(b * TT + t) * CC + h * DH + d] = y / L;
}

// -------- Kernel 5: output projection GEMM (64-row blocks, K-split 8) ----------
// grid (32, 8): x = col-tile of 64, y = k-slice of 256. Weights read once.
__global__ __launch_bounds__(256) void k_proj(
    const float* __restrict__ yws, const float* __restrict__ wp,
    float* __restrict__ part_p)
{
    __shared__ float xs[64][256];          // 64 KB
    int ns = blockIdx.x, ks = blockIdx.y;
    int tid = threadIdx.x;
    int k0 = ks * 256;
    #pragma unroll
    for (int it = 0; it < 16; ++it) {
        int slot = it * 256 + tid;
        int row = slot >> 6, c4 = slot & 63;
        *(float4*)&xs[row][c4 * 4] = *(const float4*)(yws + (size_t)row * CC + k0 + c4 * 4);
    }
    __syncthreads();

    int cp = tid & 31, rg = tid >> 5;
    int n = ns * 64 + cp * 2;
    const float* w = wp + (size_t)k0 * CC + n;
    float a[16];
    #pragma unroll
    for (int i = 0; i < 16; ++i) a[i] = 0.f;

    for (int k = 0; k < 256; k += 4) {
        float2 w0 = *(const float2*)(w);
        float2 w1 = *(const float2*)(w + CC);
        float2 w2 = *(const float2*)(w + 2 * CC);
        float2 w3 = *(const float2*)(w + 3 * CC);
        w += 4 * CC;
        #pragma unroll
        for (int m = 0; m < 8; ++m) {
            float4 xv = *(const float4*)&xs[rg * 8 + m][k];
            float s0 = a[2*m], s1 = a[2*m+1];
            s0 = fmaf(xv.x, w0.x, s0); s1 = fmaf(xv.x, w0.y, s1);
            s0 = fmaf(xv.y, w1.x, s0); s1 = fmaf(xv.y, w1.y, s1);
            s0 = fmaf(xv.z, w2.x, s0); s1 = fmaf(xv.z, w2.y, s1);
            s0 = fmaf(xv.w, w3.x, s0); s1 = fmaf(xv.w, w3.y, s1);
            a[2*m] = s0; a[2*m+1] = s1;
        }
    }
    #pragma unroll
    for (int m = 0; m < 8; ++m)
        *(float2*)(part_p + ((size_t)(ks * 64 + rg * 8 + m) * CC) + n) =
            make_float2(a[2*m], a[2*m+1]);
}

// -------- Kernel 6: sum proj partials -> out (8 splits) ------------------------
__global__ __launch_bounds__(256) void k_out(
    const float* __restrict__ part_p, float* __restrict__ out)
{
    int gt = blockIdx.x * 256 + threadIdx.x;
    float s = 0.f;
    #pragma unroll
    for (int ks = 0; ks < KSPL; ++ks) s += part_p[(size_t)ks * 64 * CC + gt];
    out[gt] = s;
}

extern "C" void kernel_launch(void* const* d_in, const int* in_sizes, int n_in,
                              void* d_out, int out_size, void* d_ws, size_t ws_size,
                              hipStream_t stream)
{
    const float* x   = (const float*)d_in[0];
    const float* ck  = (const float*)d_in[1];
    const float* cv  = (const float*)d_in[2];
    const float* wq  = (const float*)d_in[3];
    const float* wk  = (const float*)d_in[4];
    const float* wv  = (const float*)d_in[5];
    const float* wpj = (const float*)d_in[6];
    const int*   sp  = (const int*)d_in[7];
    char* ws = (char*)d_ws;
    float* qws  = (float*)(ws + Q_OFF);
    float* knew = (float*)(ws + KNEW_OFF);
    float* vnew = (float*)(ws + VNEW_OFF);
    float* yws  = (float*)(ws + Y_OFF);
    float* scr  = (float*)(ws + SCR_OFF);
    float* out  = (float*)d_out;

    hipLaunchKernelGGL(k_qkv,  dim3(48, 8),   dim3(256), 0, stream, x, wq, wk, wv, scr);
    hipLaunchKernelGGL(k_fix,  dim3(6, 64),   dim3(256), 0, stream, scr, sp, qws, knew, vnew);
    hipLaunchKernelGGL(k_attn, dim3(64 * NCH), dim3(256), 0, stream, qws, ck, cv, knew, vnew, scr);
    hipLaunchKernelGGL(k_comb, dim3(1024),    dim3(128), 0, stream, scr, yws);
    hipLaunchKernelGGL(k_proj, dim3(32, 8),   dim3(256), 0, stream, yws, wpj, scr);
    hipLaunchKernelGGL(k_out,  dim3(512),     dim3(256), 0, stream, scr, out);
}